// Round 1
// 1470.550 us; speedup vs baseline: 2.0366x; 2.0366x over previous
//
#include <hip/hip_runtime.h>

static constexpr int HID  = 4096;  // hidden size
static constexpr int SEQL = 40;
static constexpr int OUTN = 128;
static constexpr int NBLK = 256;   // 256 blocks x 1024 thr: 1 block/CU co-resident

// ---------- fp32 -> bf16 (RNE) conversion ----------
__device__ __forceinline__ unsigned f2bf(float f) {
    unsigned u = __float_as_uint(f);
    return (u + 0x7fffu + ((u >> 16) & 1u)) >> 16;
}

__global__ void convert_w_kernel(const float4* __restrict__ w,
                                 uint4* __restrict__ o, int n8) {
    int stride = gridDim.x * blockDim.x;
    for (int i = blockIdx.x * blockDim.x + threadIdx.x; i < n8; i += stride) {
        float4 a = w[2 * i];
        float4 b = w[2 * i + 1];
        uint4 r;
        r.x = f2bf(a.x) | (f2bf(a.y) << 16);
        r.y = f2bf(a.z) | (f2bf(a.w) << 16);
        r.z = f2bf(b.x) | (f2bf(b.y) << 16);
        r.w = f2bf(b.z) | (f2bf(b.w) << 16);
        o[i] = r;
    }
}

// Zero h0|h1|ctr region (contiguous dwords at start of ws).
__global__ void init_ws_kernel(unsigned* __restrict__ p, int n) {
    int i = blockIdx.x * blockDim.x + threadIdx.x;
    if (i < n) p[i] = 0u;
}

// ---------- helpers ----------
__device__ __forceinline__ float bflo(unsigned u) { return __uint_as_float(u << 16); }
__device__ __forceinline__ float bfhi(unsigned u) { return __uint_as_float(u & 0xffff0000u); }

__device__ __forceinline__ float dot8_bf(uint4 w, float4 ha, float4 hb, float acc) {
    acc = fmaf(bflo(w.x), ha.x, acc);
    acc = fmaf(bfhi(w.x), ha.y, acc);
    acc = fmaf(bflo(w.y), ha.z, acc);
    acc = fmaf(bfhi(w.y), ha.w, acc);
    acc = fmaf(bflo(w.z), hb.x, acc);
    acc = fmaf(bfhi(w.z), hb.y, acc);
    acc = fmaf(bflo(w.w), hb.z, acc);
    acc = fmaf(bfhi(w.w), hb.w, acc);
    return acc;
}

__device__ __forceinline__ float dot8_f32(float4 wa, float4 wb, float4 ha, float4 hb, float acc) {
    acc = fmaf(wa.x, ha.x, acc);
    acc = fmaf(wa.y, ha.y, acc);
    acc = fmaf(wa.z, ha.z, acc);
    acc = fmaf(wa.w, ha.w, acc);
    acc = fmaf(wb.x, hb.x, acc);
    acc = fmaf(wb.y, hb.y, acc);
    acc = fmaf(wb.z, hb.z, acc);
    acc = fmaf(wb.w, hb.w, acc);
    return acc;
}

__device__ __forceinline__ float sigm(float x) { return 1.0f / (1.0f + expf(-x)); }

// Stage the 16KB h vector into LDS.
// One 16B L2-bypassing (sc0 sc1 -> MALL-coherent) load per thread replaces the
// previous 4x scalar-dword atomic loads: 4x fewer MALL transactions for the
// 256-reader h broadcast, same freshness guarantee (never reads a stale XCD-L2
// line because sc0 sc1 loads read through to the MALL).
__device__ __forceinline__ void stage_h(float* __restrict__ hsh,
                                        const float* __restrict__ hsrc) {
    int base = threadIdx.x * 4;
    const float* p = hsrc + base;
    float4 v;
    asm volatile("global_load_dwordx4 %0, %1, off sc0 sc1\n\t"
                 "s_waitcnt vmcnt(0)"
                 : "=v"(v) : "v"(p) : "memory");
    *(float4*)(hsh + base) = v;
}

// ---------- persistent LSTM, hand-rolled MALL barrier (no grid.sync) ----------
// 256 blocks x 1024 threads = 4096 waves = one wave per hidden unit j.
// Cross-XCD h exchange + barrier counters go through device-scope atomics
// (coherent at MALL) -> no L2 writeback/invalidate per step, so the read-only
// bf16 weight stream stays cacheable in L2/L3 across all 40 steps.
//
// __launch_bounds__(1024, 4): the 16-wave block occupies 4 wave-slots/SIMD at
// 1 block/CU (fixed by the cooperative grid), so allow the full 128 VGPRs.
// Without this the compiler capped at 64 VGPRs (targeting unreachable 8
// waves/SIMD) and spilled one uint4 of the weight prefetch per thread per
// step -> 175 MB of HBM scratch writeback (flushed every step by the barrier's
// release-writeback) + an HBM-latency reload in the middle of the inner loop.
template <bool BF16>
__global__ void __launch_bounds__(1024, 4)
lstm_kernel(const float* __restrict__ x,
            const float* __restrict__ w_ih,
            const float* __restrict__ b_ih,
            const float* __restrict__ b_hh,
            const void*  __restrict__ whh,
            const float* __restrict__ dense_w,
            const float* __restrict__ dense_b,
            float* __restrict__ h0,
            float* __restrict__ h1,
            unsigned* __restrict__ ctr,
            float* __restrict__ out) {
    __shared__ float hsh[HID];  // 16 KB staged h
    const int lane = threadIdx.x & 63;
    const int j = (blockIdx.x << 4) | (threadIdx.x >> 6);  // hidden unit, 0..4095

    float wih0 = w_ih[0 * HID + j], bb0 = b_ih[0 * HID + j] + b_hh[0 * HID + j];
    float wih1 = w_ih[1 * HID + j], bb1 = b_ih[1 * HID + j] + b_hh[1 * HID + j];
    float wih2 = w_ih[2 * HID + j], bb2 = b_ih[2 * HID + j] + b_hh[2 * HID + j];
    float wih3 = w_ih[3 * HID + j], bb3 = b_ih[3 * HID + j] + b_hh[3 * HID + j];

    const uint4*  p0 = nullptr, *p1 = nullptr, *p2 = nullptr, *p3 = nullptr;
    const float4* q0 = nullptr, *q1 = nullptr, *q2 = nullptr, *q3 = nullptr;
    if constexpr (BF16) {
        p0 = (const uint4*)((const unsigned short*)whh + (size_t)(0 * HID + j) * HID);
        p1 = (const uint4*)((const unsigned short*)whh + (size_t)(1 * HID + j) * HID);
        p2 = (const uint4*)((const unsigned short*)whh + (size_t)(2 * HID + j) * HID);
        p3 = (const uint4*)((const unsigned short*)whh + (size_t)(3 * HID + j) * HID);
    } else {
        q0 = (const float4*)((const float*)whh + (size_t)(0 * HID + j) * HID);
        q1 = (const float4*)((const float*)whh + (size_t)(1 * HID + j) * HID);
        q2 = (const float4*)((const float*)whh + (size_t)(2 * HID + j) * HID);
        q3 = (const float4*)((const float*)whh + (size_t)(3 * HID + j) * HID);
    }

    float c = 0.0f;

    for (int t = 0; t < SEQL; ++t) {
        const float* hr = (t & 1) ? h1 : h0;   // t=0 reads h0 (zeros from init)
        float*       hw = (t & 1) ? h0 : h1;

        // Issue this step's first weight chunk BEFORE the h broadcast: the
        // weights don't depend on h, so their fetch latency overlaps the
        // MALL read latency of stage_h (whose vmcnt(0) drains both).
        uint4 w0, w1, w2, w3;
        if constexpr (BF16) {
            w0 = p0[lane]; w1 = p1[lane]; w2 = p2[lane]; w3 = p3[lane];
        }

        stage_h(hsh, hr);
        __syncthreads();

        const float4* hv = (const float4*)hsh;
        float xt = x[t];
        float acc0 = 0.f, acc1 = 0.f, acc2 = 0.f, acc3 = 0.f;

        if constexpr (BF16) {
            // depth-2 weight prefetch; h comes just-in-time from LDS.
#pragma unroll
            for (int it = 0; it < 8; ++it) {
                uint4 c0 = w0, c1 = w1, c2 = w2, c3 = w3;
                if (it < 7) {
                    int ni = (it + 1) * 64 + lane;
                    w0 = p0[ni]; w1 = p1[ni]; w2 = p2[ni]; w3 = p3[ni];
                }
                float4 ha = hv[it * 128 + lane * 2];
                float4 hb = hv[it * 128 + lane * 2 + 1];
                acc0 = dot8_bf(c0, ha, hb, acc0);
                acc1 = dot8_bf(c1, ha, hb, acc1);
                acc2 = dot8_bf(c2, ha, hb, acc2);
                acc3 = dot8_bf(c3, ha, hb, acc3);
            }
        } else {
#pragma unroll
            for (int it = 0; it < 8; ++it) {
                int i0 = it * 128 + lane * 2;
                float4 ha = hv[i0], hb = hv[i0 + 1];
                acc0 = dot8_f32(q0[i0], q0[i0 + 1], ha, hb, acc0);
                acc1 = dot8_f32(q1[i0], q1[i0 + 1], ha, hb, acc1);
                acc2 = dot8_f32(q2[i0], q2[i0 + 1], ha, hb, acc2);
                acc3 = dot8_f32(q3[i0], q3[i0 + 1], ha, hb, acc3);
            }
        }

#pragma unroll
        for (int off = 32; off; off >>= 1) {
            acc0 += __shfl_xor(acc0, off, 64);
            acc1 += __shfl_xor(acc1, off, 64);
            acc2 += __shfl_xor(acc2, off, 64);
            acc3 += __shfl_xor(acc3, off, 64);
        }
        float gi = acc0 + wih0 * xt + bb0;
        float gf = acc1 + wih1 * xt + bb1;
        float gg = acc2 + wih2 * xt + bb2;
        float go = acc3 + wih3 * xt + bb3;
        c = sigm(gf) * c + sigm(gi) * tanhf(gg);
        float hn = sigm(go) * tanhf(c);
        if (lane == 0)
            __hip_atomic_store(hw + j, hn, __ATOMIC_RELAXED, __HIP_MEMORY_SCOPE_AGENT);

        // ---- hand-rolled device barrier for step t ----
        // __syncthreads drains each wave's h-store (vmcnt(0) before s_barrier),
        // so one RELEASE add per block suffices; readers re-fetch h via
        // MALL-direct loads, so no acquire/L2-invalidate is needed.
        __syncthreads();
        if (threadIdx.x == 0) {
            __hip_atomic_fetch_add(ctr + t, 1u, __ATOMIC_RELEASE, __HIP_MEMORY_SCOPE_AGENT);
            while (__hip_atomic_load(ctr + t, __ATOMIC_RELAXED, __HIP_MEMORY_SCOPE_AGENT)
                   < (unsigned)NBLK)
                __builtin_amdgcn_s_sleep(2);
        }
        __syncthreads();
    }

    // Final h is in h0 (t=39 odd wrote hw=h0). Dense epilogue on blocks 0-7.
    if (blockIdx.x < OUTN / 16) {
        stage_h(hsh, h0);
        __syncthreads();
        const float4* hv  = (const float4*)hsh;
        const float4* dwr = (const float4*)(dense_w + (size_t)j * HID);
        float acc = 0.f;
#pragma unroll
        for (int it = 0; it < 8; ++it) {
            int i0 = it * 128 + lane * 2;
            acc = dot8_f32(dwr[i0], dwr[i0 + 1], hv[i0], hv[i0 + 1], acc);
        }
#pragma unroll
        for (int off = 32; off; off >>= 1) acc += __shfl_xor(acc, off, 64);
        if (lane == 0) out[j] = acc + dense_b[j];
    }
}

extern "C" void kernel_launch(void* const* d_in, const int* in_sizes, int n_in,
                              void* d_out, int out_size, void* d_ws, size_t ws_size,
                              hipStream_t stream) {
    const float* x       = (const float*)d_in[0];
    const float* w_ih    = (const float*)d_in[1];
    const float* w_hh    = (const float*)d_in[2];
    const float* b_ih    = (const float*)d_in[3];
    const float* b_hh    = (const float*)d_in[4];
    const float* dense_w = (const float*)d_in[5];
    const float* dense_b = (const float*)d_in[6];
    float* out = (float*)d_out;

    // ws layout: h0[4096] f32 | h1[4096] f32 | ctr[64] u32 | wbf bf16[4*H*H]
    float*    h0  = (float*)d_ws;
    float*    h1  = h0 + HID;
    unsigned* ctr = (unsigned*)(h1 + HID);
    unsigned short* wbf = (unsigned short*)(ctr + 64);

    // Zero h0|h1|ctr (contiguous 2*HID + 64 dwords; harness poisons ws).
    int nz = 2 * HID + 64;
    init_ws_kernel<<<(nz + 1023) / 1024, 1024, 0, stream>>>((unsigned*)d_ws, nz);

    size_t need = (size_t)(2 * HID + 64) * 4 + (size_t)4 * HID * HID * sizeof(unsigned short);
    bool use_bf16 = ws_size >= need;

    if (use_bf16) {
        int n8 = 4 * HID * HID / 8;
        convert_w_kernel<<<2048, 256, 0, stream>>>((const float4*)w_hh, (uint4*)wbf, n8);
        const void* wptr = (const void*)wbf;
        void* args[] = {(void*)&x, (void*)&w_ih, (void*)&b_ih, (void*)&b_hh,
                        (void*)&wptr, (void*)&dense_w, (void*)&dense_b,
                        (void*)&h0, (void*)&h1, (void*)&ctr, (void*)&out};
        void* fn = (void*)lstm_kernel<true>;
        hipLaunchCooperativeKernel(fn, dim3(NBLK), dim3(1024), args, 0, stream);
    } else {
        const void* wptr = (const void*)w_hh;
        void* args[] = {(void*)&x, (void*)&w_ih, (void*)&b_ih, (void*)&b_hh,
                        (void*)&wptr, (void*)&dense_w, (void*)&dense_b,
                        (void*)&h0, (void*)&h1, (void*)&ctr, (void*)&out};
        void* fn = (void*)lstm_kernel<false>;
        hipLaunchCooperativeKernel(fn, dim3(NBLK), dim3(1024), args, 0, stream);
    }
}